// Round 7
// baseline (187.569 us; speedup 1.0000x reference)
//
#include <hip/hip_runtime.h>

// ALSTM: adaptive-computation-time LSTM.
//  - sum(w)==1  =>  output = (w@H)@W_out^T + b_out ; only hbar/cbar needed.
//  - steps after halting have w==0 and cannot affect n => early exit exact
//    (b_halt=1 => p0~0.73, halts at t=1: only 2 of 101 steps run).
// R6 post-mortem: VGPR_Count pinned at 60 by __launch_bounds__(1024)
// (16 waves/CU => <=64 VGPR cliff) -- compiler can only keep ~2-4 loads in
// flight -> ~8 outstanding lines/CU -> 830 GB/s. R7: 512 thr/block
// (8 waves/CU, VGPR ceiling 256), 4 rows/wave -> ~4x in-flight loads.

#define HID    2048
#define INS    1024
#define OUTS   1024
#define MSTEPS 100
#define NBLK   256
#define NTHR   512
#define NWAVE  8
#define JPB    8      // hidden units owned per block (256*8 = 2048)
#define RPB    32     // gate rows per block (4 gates * JPB)

typedef unsigned long long u64;

__device__ __forceinline__ float wave_reduce(float v) {
    #pragma unroll
    for (int off = 32; off > 0; off >>= 1)
        v += __shfl_down(v, off, 64);
    return v;  // lane 0 holds the sum
}

__device__ __forceinline__ u64 pack_tag(unsigned tag, float v) {
    return ((u64)tag << 32) | (u64)__float_as_uint(v);
}
__device__ __forceinline__ u64 aload(const u64* p) {
    return __hip_atomic_load(p, __ATOMIC_RELAXED, __HIP_MEMORY_SCOPE_AGENT);
}
__device__ __forceinline__ void astore(u64* p, u64 v) {
    __hip_atomic_store(p, v, __ATOMIC_RELAXED, __HIP_MEMORY_SCOPE_AGENT);
}

// ws layout (floats):
//   [0..1024)    arrive slots: 256 x 16B (u64-tagged {tag, partial})
//   [1024..2048) mailboxes:    256 x 16B (u64-tagged {tag, dot})
//   [2048..4096) hbuf0 | [4096..6144) hbuf1 | [6144..8192) hbar_g
// kernel_launch zeroes the first 8192 bytes each call.

__global__ __launch_bounds__(NTHR) void alstm_kernel(
    const float* __restrict__ x,      const float* __restrict__ h0,
    const float* __restrict__ c0,     const float* __restrict__ W_ih,
    const float* __restrict__ b_ih,   const float* __restrict__ W_hh,
    const float* __restrict__ b_hh,   const float* __restrict__ w_halt,
    const float* __restrict__ b_halt, const float* __restrict__ W_out,
    const float* __restrict__ b_out,  float* __restrict__ out,
    float* __restrict__ ws)
{
    const int b    = blockIdx.x;
    const int tid  = threadIdx.x;
    const int wave = tid >> 6;
    const int lane = tid & 63;

    float* arrive = ws;                 // 256 x 4 floats (u64 in [0:2))
    float* mail   = ws + 1024;          // 256 x 4 floats
    float* hbuf0  = ws + 2048;
    float* hbuf1  = ws + 2048 + HID;
    float* hbar_g = ws + 2048 + 2 * HID;

    __shared__ float h_lds[HID];
    __shared__ float x_lds[INS];
    __shared__ float gate_lds[RPB];
    __shared__ float ihx_lds[RPB];
    __shared__ float wflag_lds[RPB];
    __shared__ float red_lds[4];
    __shared__ float bcast_lds;
    __shared__ float psum[NWAVE];

    const float bh = b_halt[0];
    const int j_own = b * JPB + tid;    // valid when tid < JPB

    // Rows for this wave: lr0 .. lr0+3
    const int lr0 = 4 * wave;

    #define SYNC_ROUND(tag_, part_, dot_) do {                                 \
        if (tid == 0) {                                                        \
            __threadfence();   /* wb: h stores reach coherence point */        \
            astore((u64*)(arrive + 4 * b), pack_tag((tag_), (part_)));         \
        }                                                                      \
        if (b == 0) {                                                          \
            float pf = 0.f;                                                    \
            if (tid < NBLK) {                                                  \
                u64 v;                                                         \
                do { v = aload((u64*)(arrive + 4 * tid)); }                    \
                while ((unsigned)(v >> 32) != (unsigned)(tag_));               \
                pf = __uint_as_float((unsigned)v);                             \
            }                                                                  \
            float s = wave_reduce(pf);                                         \
            if (lane == 0 && wave < 4) red_lds[wave] = s;                      \
            __syncthreads();                                                   \
            if (tid == 0)                                                      \
                bcast_lds = red_lds[0] + red_lds[1] + red_lds[2] + red_lds[3]; \
            __syncthreads();                                                   \
            if (tid < NBLK)                                                    \
                astore((u64*)(mail + 4 * tid), pack_tag((tag_), bcast_lds));   \
        }                                                                      \
        if (tid == 0) {                                                        \
            u64 v;                                                             \
            do { v = aload((u64*)(mail + 4 * b)); }                            \
            while ((unsigned)(v >> 32) != (unsigned)(tag_));                   \
            bcast_lds = __uint_as_float((unsigned)v);                          \
            __threadfence();   /* inv: later plain reads see fresh data */     \
        }                                                                      \
        __syncthreads();                                                       \
        (dot_) = bcast_lds;                                                    \
    } while (0)

    // ------------- stage x and h0 -------------
    ((float2*)x_lds)[tid] = ((const float2*)x)[tid];              // 512*8B=4KB
    ((float4*)h_lds)[tid] = ((const float4*)h0)[tid];             // 512*16B=8KB
    __syncthreads();

    // ih_x = W_ih[:,1:]@x + b_ih + b_hh  (4 rows/wave, from x_lds)
    #pragma unroll
    for (int rr = 0; rr < 4; ++rr) {
        const int lr = lr0 + rr;
        const int r  = (lr >> 3) * HID + b * JPB + (lr & 7);
        const float* wrow = W_ih + (size_t)r * (INS + 1) + 1;  // 1024 payload
        const int mis = (r + 1) & 3;
        const int p0  = (4 - mis) & 3;
        const int nv  = (INS - p0) >> 2;
        const float4* wv = (const float4*)(wrow + p0);
        float acc = 0.f;
        for (int i = lane; i < nv; i += 64) {
            float4 w4 = wv[i];
            int k = p0 + 4 * i;
            acc += w4.x * x_lds[k] + w4.y * x_lds[k + 1]
                 + w4.z * x_lds[k + 2] + w4.w * x_lds[k + 3];
        }
        if (lane == 0) {
            for (int k = 0; k < p0; ++k)            acc += wrow[k] * x_lds[k];
            for (int k = p0 + 4 * nv; k < INS; ++k) acc += wrow[k] * x_lds[k];
        }
        acc = wave_reduce(acc);
        if (lane == 0) {
            ihx_lds[lr]   = acc + b_ih[r] + b_hh[r];
            wflag_lds[lr] = W_ih[(size_t)r * (INS + 1)];
        }
    }

    float c_reg = 0.f, h_reg = 0.f, hbar = 0.f, cbar = 0.f;
    if (tid < JPB) c_reg = c0[j_own];

    // Row base pointers for W_hh (4 consecutive local rows)
    const float4* wr0;
    const float4* wr1;
    const float4* wr2;
    const float4* wr3;
    {
        const int r = (lr0 >> 3) * HID + b * JPB + (lr0 & 7);
        wr0 = (const float4*)(W_hh + (size_t)r * HID);
        wr1 = (const float4*)(W_hh + (size_t)(r + 1) * HID);
        wr2 = (const float4*)(W_hh + (size_t)(r + 2) * HID);
        wr3 = (const float4*)(W_hh + (size_t)(r + 3) * HID);
    }

    // ------------- recurrence with online halting -------------
    float csum = 0.f, r_halt = 0.f;
    int   n_halt = 0;
    for (int t = 0; t <= MSTEPS; ++t) {
        // h for this step already in h_lds
        {
            const float4* hv = (const float4*)h_lds;
            float a0 = 0.f, a1 = 0.f, a2 = 0.f, a3 = 0.f;
            #pragma unroll
            for (int m = 0; m < 8; ++m) {
                float4 hh = hv[lane + 64 * m];
                float4 w0 = wr0[lane + 64 * m];
                float4 w1 = wr1[lane + 64 * m];
                float4 w2 = wr2[lane + 64 * m];
                float4 w3 = wr3[lane + 64 * m];
                a0 += w0.x * hh.x + w0.y * hh.y + w0.z * hh.z + w0.w * hh.w;
                a1 += w1.x * hh.x + w1.y * hh.y + w1.z * hh.z + w1.w * hh.w;
                a2 += w2.x * hh.x + w2.y * hh.y + w2.z * hh.z + w2.w * hh.w;
                a3 += w3.x * hh.x + w3.y * hh.y + w3.z * hh.z + w3.w * hh.w;
            }
            a0 = wave_reduce(a0);
            a1 = wave_reduce(a1);
            a2 = wave_reduce(a2);
            a3 = wave_reduce(a3);
            if (lane == 0) {
                #pragma unroll
                for (int rr = 0; rr < 4; ++rr) {
                    float av = (rr == 0) ? a0 : (rr == 1) ? a1 : (rr == 2) ? a2 : a3;
                    float bb = ihx_lds[lr0 + rr];
                    if (t == 0) bb += wflag_lds[lr0 + rr];
                    gate_lds[lr0 + rr] = bb + av;
                }
            }
        }
        __syncthreads();

        float part = 0.f;
        float* hdst = (t & 1) ? hbuf1 : hbuf0;
        if (tid < JPB) {
            float iv = gate_lds[0 * JPB + tid];
            float fv = gate_lds[1 * JPB + tid];
            float gv = gate_lds[2 * JPB + tid];
            float ov = gate_lds[3 * JPB + tid];
            iv = 1.f / (1.f + expf(-iv));
            fv = 1.f / (1.f + expf(-fv));
            gv = tanhf(gv);
            ov = 1.f / (1.f + expf(-ov));
            c_reg = fv * c_reg + iv * gv;
            h_reg = ov * tanhf(c_reg);
            hdst[j_own] = h_reg;
            part = h_reg * w_halt[j_own];
        }
        part += __shfl_down(part, 4, 64);
        part += __shfl_down(part, 2, 64);
        part += __shfl_down(part, 1, 64);

        float dotv;
        SYNC_ROUND(t + 1, part, dotv);

        float p = 1.f / (1.f + expf(-(dotv + bh)));
        float prev = csum;
        csum += p;
        bool halt_now = (csum >= 1.f - 0.01f) || (t == MSTEPS);
        float wt = halt_now ? (1.f - prev) : p;
        if (tid < JPB) { hbar += wt * h_reg; cbar += wt * c_reg; }
        if (halt_now) { n_halt = t; r_halt = 1.f - prev; break; }  // uniform

        // stage h_{t+1} for next iteration
        __syncthreads();   // gate_lds/h_lds reads done
        ((float4*)h_lds)[tid] = ((const float4*)hdst)[tid];
        __syncthreads();
    }

    // ------------- epilogue -------------
    if (tid < JPB) {
        out[OUTS + j_own]       = hbar;   // h_out
        out[OUTS + HID + j_own] = cbar;   // c_out
        hbar_g[j_own] = hbar;
    }
    if (b == 0 && tid == 0) out[OUTS + 2 * HID] = (float)(n_halt + 1) + r_halt;

    float dummy;
    SYNC_ROUND(n_halt + 2, 0.f, dummy);
    (void)dummy;

    __syncthreads();
    ((float4*)h_lds)[tid] = ((const float4*)hbar_g)[tid];
    __syncthreads();

    // output = W_out @ hbar + b_out : 4 rows/block, half-row per wave
    {
        const int row  = b * 4 + (wave & 3);
        const int half = wave >> 2;             // 0 or 1
        const float4* wrow = (const float4*)(W_out + (size_t)row * HID) + half * 256;
        const float4* hv   = (const float4*)h_lds + half * 256;
        float acc = 0.f;
        #pragma unroll
        for (int m = 0; m < 4; ++m) {
            float4 w4 = wrow[lane + 64 * m];
            float4 h4 = hv[lane + 64 * m];
            acc += w4.x * h4.x + w4.y * h4.y + w4.z * h4.z + w4.w * h4.w;
        }
        acc = wave_reduce(acc);
        if (lane == 0) psum[wave] = acc;
    }
    __syncthreads();
    if (tid < 4) {
        int row = b * 4 + tid;
        out[row] = psum[tid] + psum[tid + 4] + b_out[row];
    }
    #undef SYNC_ROUND
}

extern "C" void kernel_launch(void* const* d_in, const int* in_sizes, int n_in,
                              void* d_out, int out_size, void* d_ws, size_t ws_size,
                              hipStream_t stream) {
    const float* x      = (const float*)d_in[0];
    const float* h0     = (const float*)d_in[1];
    const float* c0     = (const float*)d_in[2];
    const float* W_ih   = (const float*)d_in[3];
    const float* b_ih   = (const float*)d_in[4];
    const float* W_hh   = (const float*)d_in[5];
    const float* b_hh   = (const float*)d_in[6];
    const float* w_halt = (const float*)d_in[7];
    const float* b_halt = (const float*)d_in[8];
    const float* W_out  = (const float*)d_in[9];
    const float* b_out  = (const float*)d_in[10];
    float* out = (float*)d_out;
    float* ws  = (float*)d_ws;

    // Zero arrive slots + mailboxes (ws is poisoned 0xAA by the harness).
    hipMemsetAsync(d_ws, 0, 8192, stream);

    alstm_kernel<<<dim3(NBLK), dim3(NTHR), 0, stream>>>(
        x, h0, c0, W_ih, b_ih, W_hh, b_hh, w_halt, b_halt, W_out, b_out,
        out, ws);
}

// Round 8
// 177.621 us; speedup vs baseline: 1.0560x; 1.0560x over previous
//
#include <hip/hip_runtime.h>

// ALSTM: adaptive-computation-time LSTM.
//  - sum(w)==1  =>  output = (w@H)@W_out^T + b_out ; only hbar/cbar needed.
//  - steps after halting have w==0 and cannot affect n => early exit exact
//    (b_halt=1 => p0~0.73, halts at t=1: only 2 of 101 steps run).
// R7 post-mortem: K-loop is not MLP-bound (8 vs 16 waves: same time).
// Cost is a sum of ~10us streams: W_ih, W_hh step0, W_hh step1 re-fetch
// (sync fences invalidate L2), W_out, syncs. R8: W_hh (128 VGPR) + W_out
// (16 VGPR) pinned in registers -- legal now at 8 waves/CU (ceiling 256) --
// burst issued BEFORE the W_ih matvec so the streams overlap; KEEP asm
// ties prevent the R4/R5 rematerialization defeat.

#define HID    2048
#define INS    1024
#define OUTS   1024
#define MSTEPS 100
#define NBLK   256
#define NTHR   512
#define NWAVE  8
#define JPB    8      // hidden units owned per block (256*8 = 2048)
#define RPB    32     // gate rows per block (4 gates * JPB)

typedef unsigned long long u64;

#define KEEP4(v) asm volatile("" : "+v"((v).x), "+v"((v).y), "+v"((v).z), "+v"((v).w))

__device__ __forceinline__ float wave_reduce(float v) {
    #pragma unroll
    for (int off = 32; off > 0; off >>= 1)
        v += __shfl_down(v, off, 64);
    return v;  // lane 0 holds the sum
}

__device__ __forceinline__ u64 pack_tag(unsigned tag, float v) {
    return ((u64)tag << 32) | (u64)__float_as_uint(v);
}
__device__ __forceinline__ u64 aload(const u64* p) {
    return __hip_atomic_load(p, __ATOMIC_RELAXED, __HIP_MEMORY_SCOPE_AGENT);
}
__device__ __forceinline__ void astore(u64* p, u64 v) {
    __hip_atomic_store(p, v, __ATOMIC_RELAXED, __HIP_MEMORY_SCOPE_AGENT);
}

// ws layout (floats):
//   [0..1024)    arrive slots: 256 x 16B (u64-tagged {tag, partial})
//   [1024..2048) mailboxes:    256 x 16B (u64-tagged {tag, dot})
//   [2048..4096) hbuf0 | [4096..6144) hbuf1 | [6144..8192) hbar_g
// kernel_launch zeroes the first 8192 bytes each call.

__global__ __launch_bounds__(NTHR) void alstm_kernel(
    const float* __restrict__ x,      const float* __restrict__ h0,
    const float* __restrict__ c0,     const float* __restrict__ W_ih,
    const float* __restrict__ b_ih,   const float* __restrict__ W_hh,
    const float* __restrict__ b_hh,   const float* __restrict__ w_halt,
    const float* __restrict__ b_halt, const float* __restrict__ W_out,
    const float* __restrict__ b_out,  float* __restrict__ out,
    float* __restrict__ ws)
{
    const int b    = blockIdx.x;
    const int tid  = threadIdx.x;
    const int wave = tid >> 6;
    const int lane = tid & 63;

    float* arrive = ws;                 // 256 x 4 floats (u64 in [0:2))
    float* mail   = ws + 1024;          // 256 x 4 floats
    float* hbuf0  = ws + 2048;
    float* hbuf1  = ws + 2048 + HID;
    float* hbar_g = ws + 2048 + 2 * HID;

    __shared__ float h_lds[HID];
    __shared__ float x_lds[INS];
    __shared__ float gate_lds[RPB];
    __shared__ float ihx_lds[RPB];
    __shared__ float wflag_lds[RPB];
    __shared__ float red_lds[4];
    __shared__ float bcast_lds;
    __shared__ float psum[NWAVE];

    const float bh = b_halt[0];
    const int j_own = b * JPB + tid;    // valid when tid < JPB

    // Rows for this wave: lr0 .. lr0+3
    const int lr0 = 4 * wave;
    const int rbase = (lr0 >> 3) * HID + b * JPB + (lr0 & 7);  // rows rbase..+3

    #define SYNC_ROUND(tag_, part_, dot_) do {                                 \
        if (tid == 0) {                                                        \
            __threadfence();   /* wb: h stores reach coherence point */        \
            astore((u64*)(arrive + 4 * b), pack_tag((tag_), (part_)));         \
        }                                                                      \
        if (b == 0) {                                                          \
            float pf = 0.f;                                                    \
            if (tid < NBLK) {                                                  \
                u64 v;                                                         \
                do { v = aload((u64*)(arrive + 4 * tid)); }                    \
                while ((unsigned)(v >> 32) != (unsigned)(tag_));               \
                pf = __uint_as_float((unsigned)v);                             \
            }                                                                  \
            float s = wave_reduce(pf);                                         \
            if (lane == 0 && wave < 4) red_lds[wave] = s;                      \
            __syncthreads();                                                   \
            if (tid == 0)                                                      \
                bcast_lds = red_lds[0] + red_lds[1] + red_lds[2] + red_lds[3]; \
            __syncthreads();                                                   \
            if (tid < NBLK)                                                    \
                astore((u64*)(mail + 4 * tid), pack_tag((tag_), bcast_lds));   \
        }                                                                      \
        if (tid == 0) {                                                        \
            u64 v;                                                             \
            do { v = aload((u64*)(mail + 4 * b)); }                            \
            while ((unsigned)(v >> 32) != (unsigned)(tag_));                   \
            bcast_lds = __uint_as_float((unsigned)v);                          \
            __threadfence();   /* inv: later plain reads see fresh data */     \
        }                                                                      \
        __syncthreads();                                                       \
        (dot_) = bcast_lds;                                                    \
    } while (0)

    // ---- W_hh + W_out register burst FIRST (latency hidden by W_ih work) ----
    float4 w0r[8], w1r[8], w2r[8], w3r[8];
    {
        const float4* p0 = (const float4*)(W_hh + (size_t)rbase * HID);
        const float4* p1 = (const float4*)(W_hh + (size_t)(rbase + 1) * HID);
        const float4* p2 = (const float4*)(W_hh + (size_t)(rbase + 2) * HID);
        const float4* p3 = (const float4*)(W_hh + (size_t)(rbase + 3) * HID);
        #pragma unroll
        for (int m = 0; m < 8; ++m) {
            w0r[m] = p0[lane + 64 * m];
            w1r[m] = p1[lane + 64 * m];
            w2r[m] = p2[lane + 64 * m];
            w3r[m] = p3[lane + 64 * m];
        }
    }
    const int orow  = b * 4 + (wave & 3);   // W_out row for epilogue
    const int ohalf = wave >> 2;            // 0 or 1
    float4 wor[4];
    {
        const float4* po = (const float4*)(W_out + (size_t)orow * HID) + ohalf * 256;
        #pragma unroll
        for (int m = 0; m < 4; ++m) wor[m] = po[lane + 64 * m];
    }

    // ------------- stage x and h0 -------------
    ((float2*)x_lds)[tid] = ((const float2*)x)[tid];
    ((float4*)h_lds)[tid] = ((const float4*)h0)[tid];
    __syncthreads();

    // ih_x = W_ih[:,1:]@x + b_ih + b_hh  (4 rows/wave, from x_lds) --
    // executes while the register burst is still landing.
    #pragma unroll
    for (int rr = 0; rr < 4; ++rr) {
        const int lr = lr0 + rr;
        const int r  = (lr >> 3) * HID + b * JPB + (lr & 7);
        const float* wrow = W_ih + (size_t)r * (INS + 1) + 1;  // 1024 payload
        const int mis = (r + 1) & 3;
        const int p0  = (4 - mis) & 3;
        const int nv  = (INS - p0) >> 2;
        const float4* wv = (const float4*)(wrow + p0);
        float acc = 0.f;
        for (int i = lane; i < nv; i += 64) {
            float4 w4 = wv[i];
            int k = p0 + 4 * i;
            acc += w4.x * x_lds[k] + w4.y * x_lds[k + 1]
                 + w4.z * x_lds[k + 2] + w4.w * x_lds[k + 3];
        }
        if (lane == 0) {
            for (int k = 0; k < p0; ++k)            acc += wrow[k] * x_lds[k];
            for (int k = p0 + 4 * nv; k < INS; ++k) acc += wrow[k] * x_lds[k];
        }
        acc = wave_reduce(acc);
        if (lane == 0) {
            ihx_lds[lr]   = acc + b_ih[r] + b_hh[r];
            wflag_lds[lr] = W_ih[(size_t)r * (INS + 1)];
        }
    }

    // Pin the burst: opaque register redefinition (defeats rematerialization).
    #pragma unroll
    for (int m = 0; m < 8; ++m) {
        KEEP4(w0r[m]); KEEP4(w1r[m]); KEEP4(w2r[m]); KEEP4(w3r[m]);
    }
    #pragma unroll
    for (int m = 0; m < 4; ++m) KEEP4(wor[m]);

    float c_reg = 0.f, h_reg = 0.f, hbar = 0.f, cbar = 0.f;
    if (tid < JPB) c_reg = c0[j_own];

    // ------------- recurrence with online halting -------------
    float csum = 0.f, r_halt = 0.f;
    int   n_halt = 0;
    for (int t = 0; t <= MSTEPS; ++t) {
        // h for this step already in h_lds
        {
            const float4* hv = (const float4*)h_lds;
            float a0 = 0.f, a1 = 0.f, a2 = 0.f, a3 = 0.f;
            #pragma unroll
            for (int m = 0; m < 8; ++m) {
                float4 hh = hv[lane + 64 * m];
                a0 += w0r[m].x * hh.x + w0r[m].y * hh.y + w0r[m].z * hh.z + w0r[m].w * hh.w;
                a1 += w1r[m].x * hh.x + w1r[m].y * hh.y + w1r[m].z * hh.z + w1r[m].w * hh.w;
                a2 += w2r[m].x * hh.x + w2r[m].y * hh.y + w2r[m].z * hh.z + w2r[m].w * hh.w;
                a3 += w3r[m].x * hh.x + w3r[m].y * hh.y + w3r[m].z * hh.z + w3r[m].w * hh.w;
            }
            a0 = wave_reduce(a0);
            a1 = wave_reduce(a1);
            a2 = wave_reduce(a2);
            a3 = wave_reduce(a3);
            if (lane == 0) {
                float bb0 = ihx_lds[lr0 + 0], bb1 = ihx_lds[lr0 + 1];
                float bb2 = ihx_lds[lr0 + 2], bb3 = ihx_lds[lr0 + 3];
                if (t == 0) {
                    bb0 += wflag_lds[lr0 + 0]; bb1 += wflag_lds[lr0 + 1];
                    bb2 += wflag_lds[lr0 + 2]; bb3 += wflag_lds[lr0 + 3];
                }
                gate_lds[lr0 + 0] = bb0 + a0;
                gate_lds[lr0 + 1] = bb1 + a1;
                gate_lds[lr0 + 2] = bb2 + a2;
                gate_lds[lr0 + 3] = bb3 + a3;
            }
        }
        __syncthreads();

        float part = 0.f;
        float* hdst = (t & 1) ? hbuf1 : hbuf0;
        if (tid < JPB) {
            float iv = gate_lds[0 * JPB + tid];
            float fv = gate_lds[1 * JPB + tid];
            float gv = gate_lds[2 * JPB + tid];
            float ov = gate_lds[3 * JPB + tid];
            iv = 1.f / (1.f + expf(-iv));
            fv = 1.f / (1.f + expf(-fv));
            gv = tanhf(gv);
            ov = 1.f / (1.f + expf(-ov));
            c_reg = fv * c_reg + iv * gv;
            h_reg = ov * tanhf(c_reg);
            hdst[j_own] = h_reg;
            part = h_reg * w_halt[j_own];
        }
        part += __shfl_down(part, 4, 64);
        part += __shfl_down(part, 2, 64);
        part += __shfl_down(part, 1, 64);

        float dotv;
        SYNC_ROUND(t + 1, part, dotv);

        float p = 1.f / (1.f + expf(-(dotv + bh)));
        float prev = csum;
        csum += p;
        bool halt_now = (csum >= 1.f - 0.01f) || (t == MSTEPS);
        float wt = halt_now ? (1.f - prev) : p;
        if (tid < JPB) { hbar += wt * h_reg; cbar += wt * c_reg; }
        if (halt_now) { n_halt = t; r_halt = 1.f - prev; break; }  // uniform

        // stage h_{t+1} for next iteration
        __syncthreads();   // gate_lds/h_lds reads done
        ((float4*)h_lds)[tid] = ((const float4*)hdst)[tid];
        __syncthreads();
    }

    // ------------- epilogue -------------
    if (tid < JPB) {
        out[OUTS + j_own]       = hbar;   // h_out
        out[OUTS + HID + j_own] = cbar;   // c_out
        hbar_g[j_own] = hbar;
    }
    if (b == 0 && tid == 0) out[OUTS + 2 * HID] = (float)(n_halt + 1) + r_halt;

    float dummy;
    SYNC_ROUND(n_halt + 2, 0.f, dummy);
    (void)dummy;

    __syncthreads();
    ((float4*)h_lds)[tid] = ((const float4*)hbar_g)[tid];
    __syncthreads();

    // output = W_out @ hbar + b_out : weights already in registers
    {
        const float4* hv = (const float4*)h_lds + ohalf * 256;
        float acc = 0.f;
        #pragma unroll
        for (int m = 0; m < 4; ++m) {
            float4 h4 = hv[lane + 64 * m];
            acc += wor[m].x * h4.x + wor[m].y * h4.y
                 + wor[m].z * h4.z + wor[m].w * h4.w;
        }
        acc = wave_reduce(acc);
        if (lane == 0) psum[wave] = acc;
    }
    __syncthreads();
    if (tid < 4) {
        int row = b * 4 + tid;
        out[row] = psum[tid] + psum[tid + 4] + b_out[row];
    }
    #undef SYNC_ROUND
}

extern "C" void kernel_launch(void* const* d_in, const int* in_sizes, int n_in,
                              void* d_out, int out_size, void* d_ws, size_t ws_size,
                              hipStream_t stream) {
    const float* x      = (const float*)d_in[0];
    const float* h0     = (const float*)d_in[1];
    const float* c0     = (const float*)d_in[2];
    const float* W_ih   = (const float*)d_in[3];
    const float* b_ih   = (const float*)d_in[4];
    const float* W_hh   = (const float*)d_in[5];
    const float* b_hh   = (const float*)d_in[6];
    const float* w_halt = (const float*)d_in[7];
    const float* b_halt = (const float*)d_in[8];
    const float* W_out  = (const float*)d_in[9];
    const float* b_out  = (const float*)d_in[10];
    float* out = (float*)d_out;
    float* ws  = (float*)d_ws;

    // Zero arrive slots + mailboxes (ws is poisoned 0xAA by the harness).
    hipMemsetAsync(d_ws, 0, 8192, stream);

    alstm_kernel<<<dim3(NBLK), dim3(NTHR), 0, stream>>>(
        x, h0, c0, W_ih, b_ih, W_hh, b_hh, w_halt, b_halt, W_out, b_out,
        out, ws);
}